// Round 1
// baseline (311.761 us; speedup 1.0000x reference)
//
#include <hip/hip_runtime.h>

// FiringRateModel: T=2048 sequential steps over B=8192 independent chains,
// N=64 state dims. State folded with w:  s_n = v_n * w_n.
//   s_n <- (1-ds_n) s_n + cur*(a_n w_n) + f*(1000 b_n w_n);  z = sum_n s_n
//   f = relu(200*tanh(poly(z/100 - g_b/100)))
// 16 lanes/chain, 4 states/lane; 16-lane DPP all-reduce for z.

#define TT 2048
#define BB 8192
#define NN 64

template<int CTRL>
__device__ __forceinline__ float dpp_movf(float x) {
    return __int_as_float(__builtin_amdgcn_update_dpp(
        0, __float_as_int(x), CTRL, 0xF, 0xF, true));
}

// all-reduce sum across a 16-lane row (groups are row-aligned: g = tid & 15)
__device__ __forceinline__ float allreduce16(float z) {
    z += dpp_movf<0xB1>(z);   // quad_perm [1,0,3,2] : + x^1
    z += dpp_movf<0x4E>(z);   // quad_perm [2,3,0,1] : + x^2  -> quad sums
    z += dpp_movf<0x124>(z);  // row_ror:4           : + neighbor quad
    z += dpp_movf<0x128>(z);  // row_ror:8           : + opposite pair -> total
    return z;
}

#define STEP(cv, so) do {                                               \
    float u0 = fmaf((cv), aw0, f * bw0); s0 = fmaf(d10, s0, u0);        \
    float u1 = fmaf((cv), aw1, f * bw1); s1 = fmaf(d11, s1, u1);        \
    float u2 = fmaf((cv), aw2, f * bw2); s2 = fmaf(d12, s2, u2);        \
    float u3 = fmaf((cv), aw3, f * bw3); s3 = fmaf(d13, s3, u3);        \
    float z = (s0 + s1) + (s2 + s3);                                    \
    z = allreduce16(z);                                                 \
    float xx = fmaf(z, 0.01f, ngb01);                                   \
    float pl = fmaf(c25, xx, c24);                                      \
    pl = fmaf(pl, xx, c23);                                             \
    pl = fmaf(pl, xx, c22);                                             \
    pl = fmaf(pl, xx, c21);                                             \
    pl = fmaf(pl, xx, c20);                                             \
    float ee = __builtin_amdgcn_exp2f(pl * -2.885390081777927f);        \
    float rr = (1.0f - ee) * __builtin_amdgcn_rcpf(1.0f + ee);          \
    f = pl > 0.0f ? 200.0f * rr : 0.0f;                                 \
    if (g == 0) opt[(so) * BB] = f;                                     \
} while (0)

__global__ __launch_bounds__(256) void frm_kernel(
    const float* __restrict__ cur, const float* __restrict__ fs0,
    const float* __restrict__ av,  const float* __restrict__ bv,
    const float* __restrict__ wv,  const float* __restrict__ dsv,
    const float* __restrict__ pcv, const float* __restrict__ gbv,
    float* __restrict__ out)
{
    const int tid   = blockIdx.x * 256 + threadIdx.x;
    const int chain = tid >> 4;            // batch index b
    const int g     = threadIdx.x & 15;    // lane within 16-lane group (row-aligned)

    const int n0 = g * 4;                  // this lane's 4 state indices
    const float w0 = wv[n0+0], w1 = wv[n0+1], w2 = wv[n0+2], w3 = wv[n0+3];
    const float d10 = 1.0f - dsv[n0+0], d11 = 1.0f - dsv[n0+1];
    const float d12 = 1.0f - dsv[n0+2], d13 = 1.0f - dsv[n0+3];
    const float aw0 = av[n0+0]*w0, aw1 = av[n0+1]*w1;
    const float aw2 = av[n0+2]*w2, aw3 = av[n0+3]*w3;
    const float bw0 = 1000.0f*bv[n0+0]*w0, bw1 = 1000.0f*bv[n0+1]*w1;
    const float bw2 = 1000.0f*bv[n0+2]*w2, bw3 = 1000.0f*bv[n0+3]*w3;

    const float c20 = pcv[0]*pcv[0], c21 = pcv[1]*pcv[1], c22 = pcv[2]*pcv[2];
    const float c23 = pcv[3]*pcv[3], c24 = pcv[4]*pcv[4], c25 = pcv[5]*pcv[5];
    const float ngb01 = -gbv[0] * 0.01f;

    float f  = fs0[chain];
    float s0 = 0.0f, s1 = 0.0f, s2 = 0.0f, s3 = 0.0f;

    const float* cpt = cur + chain;
    float*       opt = out + chain;

    // distance-8 register prefetch pipeline, two 4-wide banks, unroll 8
    float p0 = cpt[0*BB], p1 = cpt[1*BB], p2 = cpt[2*BB], p3 = cpt[3*BB];
    float q0 = cpt[4*BB], q1 = cpt[5*BB], q2 = cpt[6*BB], q3 = cpt[7*BB];
    cpt += 8 * BB;                         // points at t+8

    for (int t = 0; t + 16 <= TT; t += 8) {
        float c0 = p0, c1 = p1, cc2 = p2, c3 = p3;
        p0 = cpt[0*BB]; p1 = cpt[1*BB]; p2 = cpt[2*BB]; p3 = cpt[3*BB];
        STEP(c0, 0); STEP(c1, 1); STEP(cc2, 2); STEP(c3, 3);
        opt += 4 * BB;
        c0 = q0; c1 = q1; cc2 = q2; c3 = q3;
        q0 = cpt[4*BB]; q1 = cpt[5*BB]; q2 = cpt[6*BB]; q3 = cpt[7*BB];
        STEP(c0, 0); STEP(c1, 1); STEP(cc2, 2); STEP(c3, 3);
        opt += 4 * BB;
        cpt += 8 * BB;
    }
    // epilogue: p holds steps T-8..T-5, q holds T-4..T-1
    STEP(p0, 0); STEP(p1, 1); STEP(p2, 2); STEP(p3, 3);
    opt += 4 * BB;
    STEP(q0, 0); STEP(q1, 1); STEP(q2, 2); STEP(q3, 3);
}

extern "C" void kernel_launch(void* const* d_in, const int* in_sizes, int n_in,
                              void* d_out, int out_size, void* d_ws, size_t ws_size,
                              hipStream_t stream) {
    const float* cur = (const float*)d_in[0];
    const float* fs0 = (const float*)d_in[1];
    const float* a   = (const float*)d_in[2];
    const float* b   = (const float*)d_in[3];
    const float* w   = (const float*)d_in[4];
    const float* ds  = (const float*)d_in[5];
    const float* pc  = (const float*)d_in[6];
    const float* gb  = (const float*)d_in[7];
    float* out = (float*)d_out;

    const int threads = 256;
    const int grid = (BB * 16) / threads;  // 512 blocks = 2048 waves
    frm_kernel<<<grid, threads, 0, stream>>>(cur, fs0, a, b, w, ds, pc, gb, out);
}

// Round 2
// 290.089 us; speedup vs baseline: 1.0747x; 1.0747x over previous
//
#include <hip/hip_runtime.h>

// FiringRateModel: T=2048 sequential steps over B=8192 independent chains,
// N=64 state dims. State folded with w:  s_n = v_n * w_n.
//   s_n <- (1-ds_n) s_n + cur*(a_n w_n) + f*(1000 b_n w_n);  z = sum_n s_n
//   f = 200*tanh(max(poly(z/100 - g_b/100), 0))   [== relu(200 tanh(poly))]
// 16 lanes/chain, 4 states/lane (2x float2 packed); fused-DPP 16-lane allreduce.

#define TT 2048
#define BB 8192

typedef float v2f __attribute__((ext_vector_type(2)));

// Fused DPP butterfly adds: out = dpp(z) + z, single v_add_f32_dpp each.
// All 64 lanes active at these points; source lanes always valid in-row.
__device__ __forceinline__ float dpp_add_x1(float z) {
    float o;
    asm("v_add_f32 %0, %1, %2 quad_perm:[1,0,3,2] row_mask:0xf bank_mask:0xf"
        : "=v"(o) : "v"(z), "v"(z));
    return o;
}
__device__ __forceinline__ float dpp_add_x2(float z) {
    float o;
    asm("v_add_f32 %0, %1, %2 quad_perm:[2,3,0,1] row_mask:0xf bank_mask:0xf"
        : "=v"(o) : "v"(z), "v"(z));
    return o;
}
__device__ __forceinline__ float dpp_add_r4(float z) {
    float o;
    asm("v_add_f32 %0, %1, %2 row_ror:4 row_mask:0xf bank_mask:0xf"
        : "=v"(o) : "v"(z), "v"(z));
    return o;
}
__device__ __forceinline__ float dpp_add_r8(float z) {
    float o;
    asm("v_add_f32 %0, %1, %2 row_ror:8 row_mask:0xf bank_mask:0xf"
        : "=v"(o) : "v"(z), "v"(z));
    return o;
}

__device__ __forceinline__ float allreduce16(float z) {
    z = dpp_add_x1(z);   // + lane^1
    z = dpp_add_x2(z);   // + lane^2   -> quad sums
    z = dpp_add_r4(z);   // + next quad
    z = dpp_add_r8(z);   // + opposite pair -> row-group total
    return z;
}

#define STEP(cv, so) do {                                               \
    v2f f2 = { f, f };                                                  \
    v2f c2 = { (cv), (cv) };                                            \
    v2f u01 = __builtin_elementwise_fma(c2, aw01, f2 * bw01);           \
    v2f u23 = __builtin_elementwise_fma(c2, aw23, f2 * bw23);           \
    s01 = __builtin_elementwise_fma(d01, s01, u01);                     \
    s23 = __builtin_elementwise_fma(d23, s23, u23);                     \
    v2f zz = s01 + s23;                                                 \
    float z = zz.x + zz.y;                                              \
    z = allreduce16(z);                                                 \
    float xx = fmaf(z, 0.01f, ngb01);                                   \
    float pl = fmaf(c25, xx, c24);                                      \
    pl = fmaf(pl, xx, c23);                                             \
    pl = fmaf(pl, xx, c22);                                             \
    pl = fmaf(pl, xx, c21);                                             \
    pl = fmaf(pl, xx, c20);                                             \
    pl = fmaxf(pl, 0.0f);                                               \
    float ee = __builtin_amdgcn_exp2f(pl * -2.885390081777927f);        \
    float nn = fmaf(ee, -200.0f, 200.0f);                               \
    f = nn * __builtin_amdgcn_rcpf(1.0f + ee);                          \
    if (g == 0) opt[(so) * BB] = f;                                     \
} while (0)

__global__ __launch_bounds__(256) void frm_kernel(
    const float* __restrict__ cur, const float* __restrict__ fs0,
    const float* __restrict__ av,  const float* __restrict__ bv,
    const float* __restrict__ wv,  const float* __restrict__ dsv,
    const float* __restrict__ pcv, const float* __restrict__ gbv,
    float* __restrict__ out)
{
    const int tid   = blockIdx.x * 256 + threadIdx.x;
    const int chain = tid >> 4;            // batch index b
    const int g     = threadIdx.x & 15;    // lane within 16-lane group (row-aligned)

    const int n0 = g * 4;                  // this lane's 4 state indices
    const float w0 = wv[n0+0], w1 = wv[n0+1], w2 = wv[n0+2], w3 = wv[n0+3];
    const v2f d01 = { 1.0f - dsv[n0+0], 1.0f - dsv[n0+1] };
    const v2f d23 = { 1.0f - dsv[n0+2], 1.0f - dsv[n0+3] };
    const v2f aw01 = { av[n0+0]*w0, av[n0+1]*w1 };
    const v2f aw23 = { av[n0+2]*w2, av[n0+3]*w3 };
    const v2f bw01 = { 1000.0f*bv[n0+0]*w0, 1000.0f*bv[n0+1]*w1 };
    const v2f bw23 = { 1000.0f*bv[n0+2]*w2, 1000.0f*bv[n0+3]*w3 };

    const float c20 = pcv[0]*pcv[0], c21 = pcv[1]*pcv[1], c22 = pcv[2]*pcv[2];
    const float c23 = pcv[3]*pcv[3], c24 = pcv[4]*pcv[4], c25 = pcv[5]*pcv[5];
    const float ngb01 = -gbv[0] * 0.01f;

    float f  = fs0[chain];
    v2f s01 = { 0.0f, 0.0f }, s23 = { 0.0f, 0.0f };

    const float* cpt = cur + chain;
    float*       opt = out + chain;

    // distance-8 register prefetch pipeline, two 4-wide banks, unroll 8
    float p0 = cpt[0*BB], p1 = cpt[1*BB], p2 = cpt[2*BB], p3 = cpt[3*BB];
    float q0 = cpt[4*BB], q1 = cpt[5*BB], q2 = cpt[6*BB], q3 = cpt[7*BB];
    cpt += 8 * BB;                         // points at t+8

    for (int t = 0; t + 16 <= TT; t += 8) {
        float c0 = p0, c1 = p1, cc2 = p2, c3 = p3;
        p0 = cpt[0*BB]; p1 = cpt[1*BB]; p2 = cpt[2*BB]; p3 = cpt[3*BB];
        STEP(c0, 0); STEP(c1, 1); STEP(cc2, 2); STEP(c3, 3);
        opt += 4 * BB;
        c0 = q0; c1 = q1; cc2 = q2; c3 = q3;
        q0 = cpt[4*BB]; q1 = cpt[5*BB]; q2 = cpt[6*BB]; q3 = cpt[7*BB];
        STEP(c0, 0); STEP(c1, 1); STEP(cc2, 2); STEP(c3, 3);
        opt += 4 * BB;
        cpt += 8 * BB;
    }
    // epilogue: p holds steps T-8..T-5, q holds T-4..T-1
    STEP(p0, 0); STEP(p1, 1); STEP(p2, 2); STEP(p3, 3);
    opt += 4 * BB;
    STEP(q0, 0); STEP(q1, 1); STEP(q2, 2); STEP(q3, 3);
}

extern "C" void kernel_launch(void* const* d_in, const int* in_sizes, int n_in,
                              void* d_out, int out_size, void* d_ws, size_t ws_size,
                              hipStream_t stream) {
    const float* cur = (const float*)d_in[0];
    const float* fs0 = (const float*)d_in[1];
    const float* a   = (const float*)d_in[2];
    const float* b   = (const float*)d_in[3];
    const float* w   = (const float*)d_in[4];
    const float* ds  = (const float*)d_in[5];
    const float* pc  = (const float*)d_in[6];
    const float* gb  = (const float*)d_in[7];
    float* out = (float*)d_out;

    const int threads = 256;
    const int grid = (BB * 16) / threads;  // 512 blocks = 2048 waves, 2/SIMD
    frm_kernel<<<grid, threads, 0, stream>>>(cur, fs0, a, b, w, ds, pc, gb, out);
}

// Round 3
// 283.379 us; speedup vs baseline: 1.1002x; 1.0237x over previous
//
#include <hip/hip_runtime.h>

// FiringRateModel, z-recurrence formulation.
// State sigma_n = d_n * s_n  (s folded with w, then with d):
//   sigma_t = d*sigma_{t-1} + c_t*(d*aw) + f_{t-1}*(d*bw)
//   z_{t+1} = Sum(sigma_t) + c_{t+1}*SA + f_t*SB     (SA=Sum aw, SB=Sum bw)
//   f_t = 200*tanh(max(poly(z_t/100 - g_b/100), 0))
// Critical path per step = activation + 1 fma; sigma/allreduce path runs
// in parallel (depends only on f_{t-1}).
// 16 lanes/chain, 4 states/lane (2x float2 packed); fused-DPP allreduce.

#define TT 2048
#define BB 8192

typedef float v2f __attribute__((ext_vector_type(2)));

__device__ __forceinline__ float dpp_add_x1(float z) {
    float o;
    asm("v_add_f32 %0, %1, %2 quad_perm:[1,0,3,2] row_mask:0xf bank_mask:0xf"
        : "=v"(o) : "v"(z), "v"(z));
    return o;
}
__device__ __forceinline__ float dpp_add_x2(float z) {
    float o;
    asm("v_add_f32 %0, %1, %2 quad_perm:[2,3,0,1] row_mask:0xf bank_mask:0xf"
        : "=v"(o) : "v"(z), "v"(z));
    return o;
}
__device__ __forceinline__ float dpp_add_r4(float z) {
    float o;
    asm("v_add_f32 %0, %1, %2 row_ror:4 row_mask:0xf bank_mask:0xf"
        : "=v"(o) : "v"(z), "v"(z));
    return o;
}
__device__ __forceinline__ float dpp_add_r8(float z) {
    float o;
    asm("v_add_f32 %0, %1, %2 row_ror:8 row_mask:0xf bank_mask:0xf"
        : "=v"(o) : "v"(z), "v"(z));
    return o;
}
__device__ __forceinline__ float allreduce16(float z) {
    z = dpp_add_x1(z);
    z = dpp_add_x2(z);
    z = dpp_add_r4(z);
    z = dpp_add_r8(z);
    return z;
}

// One step: consumes z (=z_t), produces FOUT (=f_t) and next z (=z_{t+1}).
// Activation path and sigma/reduce path are independent -> scheduler interleaves.
#define STEP(ccur, cnext, so, FIN, FOUT) do {                           \
    float xx = fmaf(z, 0.01f, ngb01);                                   \
    float x2 = xx * xx;                                                 \
    float t1 = fmaf(k5, xx, k4);                                        \
    float t2 = fmaf(k3, xx, k2);                                        \
    float t3 = fmaf(k1, xx, k0);                                        \
    float pl = fmaf(t1, x2, t2);                                        \
    pl = fmaf(pl, x2, t3);                                              \
    pl = fmaxf(pl, 0.0f);                                               \
    float ee = __builtin_amdgcn_exp2f(pl * -2.885390081777927f);        \
    FOUT = fmaf(ee, -200.0f, 200.0f) * __builtin_amdgcn_rcpf(1.0f + ee);\
    v2f f2 = { FIN, FIN };                                              \
    v2f c2 = { (ccur), (ccur) };                                        \
    sg01 = __builtin_elementwise_fma(d01, sg01,                         \
             __builtin_elementwise_fma(c2, Ap01, f2 * Bp01));           \
    sg23 = __builtin_elementwise_fma(d23, sg23,                         \
             __builtin_elementwise_fma(c2, Ap23, f2 * Bp23));           \
    v2f ss = sg01 + sg23;                                               \
    float S = allreduce16(ss.x + ss.y);                                 \
    z = fmaf(FOUT, SB, fmaf((cnext), SA, S));                           \
    if (g == 0) outp[obase + (so) * BB + chain] = FOUT;                 \
} while (0)

__global__ __launch_bounds__(256, 1) void frm_kernel(
    const float* __restrict__ cur, const float* __restrict__ fs0,
    const float* __restrict__ av,  const float* __restrict__ bv,
    const float* __restrict__ wv,  const float* __restrict__ dsv,
    const float* __restrict__ pcv, const float* __restrict__ gbv,
    float* __restrict__ outp)
{
    const int tid   = blockIdx.x * 256 + threadIdx.x;
    const int chain = tid >> 4;            // batch index b
    const int g     = threadIdx.x & 15;    // lane in 16-lane row-aligned group

    const int n0 = g * 4;
    const float w0 = wv[n0+0], w1 = wv[n0+1], w2 = wv[n0+2], w3 = wv[n0+3];
    const v2f d01 = { 1.0f - dsv[n0+0], 1.0f - dsv[n0+1] };
    const v2f d23 = { 1.0f - dsv[n0+2], 1.0f - dsv[n0+3] };
    const v2f aw01 = { av[n0+0]*w0, av[n0+1]*w1 };
    const v2f aw23 = { av[n0+2]*w2, av[n0+3]*w3 };
    const v2f bw01 = { 1000.0f*bv[n0+0]*w0, 1000.0f*bv[n0+1]*w1 };
    const v2f bw23 = { 1000.0f*bv[n0+2]*w2, 1000.0f*bv[n0+3]*w3 };
    const v2f Ap01 = d01 * aw01, Ap23 = d23 * aw23;   // d*aw
    const v2f Bp01 = d01 * bw01, Bp23 = d23 * bw23;   // d*bw

    // SA = sum_n aw_n, SB = sum_n bw_n (uniform across group after allreduce)
    const float SA = allreduce16((aw01.x + aw01.y) + (aw23.x + aw23.y));
    const float SB = allreduce16((bw01.x + bw01.y) + (bw23.x + bw23.y));

    const float k0 = pcv[0]*pcv[0], k1 = pcv[1]*pcv[1], k2 = pcv[2]*pcv[2];
    const float k3 = pcv[3]*pcv[3], k4 = pcv[4]*pcv[4], k5 = pcv[5]*pcv[5];
    const float ngb01 = -gbv[0] * 0.01f;

    float fA = fs0[chain];
    float fB;
    v2f sg01 = { 0.0f, 0.0f }, sg23 = { 0.0f, 0.0f };

    const float* cpt = cur + chain;

    // prefetch first 16 currents
    float P0 = cpt[0*BB], P1 = cpt[1*BB], P2 = cpt[2*BB], P3 = cpt[3*BB];
    float P4 = cpt[4*BB], P5 = cpt[5*BB], P6 = cpt[6*BB], P7 = cpt[7*BB];
    float Q0 = cpt[8*BB], Q1 = cpt[9*BB], Q2 = cpt[10*BB], Q3 = cpt[11*BB];
    float Q4 = cpt[12*BB], Q5 = cpt[13*BB], Q6 = cpt[14*BB], Q7 = cpt[15*BB];

    // z_0 = c_0*SA + fs0*SB  (sigma_{-1} = 0)
    float z = fmaf(fA, SB, P0 * SA);

    int obase = 0;  // element offset of row t in out/cur
    for (int t = 0; t + 32 <= TT; t += 16) {
        STEP(P0, P1, 0, fA, fB);  STEP(P1, P2, 1, fB, fA);
        STEP(P2, P3, 2, fA, fB);  STEP(P3, P4, 3, fB, fA);
        STEP(P4, P5, 4, fA, fB);  STEP(P5, P6, 5, fB, fA);
        STEP(P6, P7, 6, fA, fB);  STEP(P7, Q0, 7, fB, fA);
        P0 = cpt[obase + 16*BB]; P1 = cpt[obase + 17*BB];
        P2 = cpt[obase + 18*BB]; P3 = cpt[obase + 19*BB];
        P4 = cpt[obase + 20*BB]; P5 = cpt[obase + 21*BB];
        P6 = cpt[obase + 22*BB]; P7 = cpt[obase + 23*BB];
        STEP(Q0, Q1, 8, fA, fB);  STEP(Q1, Q2, 9, fB, fA);
        STEP(Q2, Q3, 10, fA, fB); STEP(Q3, Q4, 11, fB, fA);
        STEP(Q4, Q5, 12, fA, fB); STEP(Q5, Q6, 13, fB, fA);
        STEP(Q6, Q7, 14, fA, fB); STEP(Q7, P0, 15, fB, fA);
        Q0 = cpt[obase + 24*BB]; Q1 = cpt[obase + 25*BB];
        Q2 = cpt[obase + 26*BB]; Q3 = cpt[obase + 27*BB];
        Q4 = cpt[obase + 28*BB]; Q5 = cpt[obase + 29*BB];
        Q6 = cpt[obase + 30*BB]; Q7 = cpt[obase + 31*BB];
        obase += 16 * BB;
    }
    // epilogue: steps TT-16 .. TT-1 entirely from registers
    STEP(P0, P1, 0, fA, fB);  STEP(P1, P2, 1, fB, fA);
    STEP(P2, P3, 2, fA, fB);  STEP(P3, P4, 3, fB, fA);
    STEP(P4, P5, 4, fA, fB);  STEP(P5, P6, 5, fB, fA);
    STEP(P6, P7, 6, fA, fB);  STEP(P7, Q0, 7, fB, fA);
    STEP(Q0, Q1, 8, fA, fB);  STEP(Q1, Q2, 9, fB, fA);
    STEP(Q2, Q3, 10, fA, fB); STEP(Q3, Q4, 11, fB, fA);
    STEP(Q4, Q5, 12, fA, fB); STEP(Q5, Q6, 13, fB, fA);
    STEP(Q6, Q7, 14, fA, fB); STEP(Q7, 0.0f, 15, fB, fA);
}

extern "C" void kernel_launch(void* const* d_in, const int* in_sizes, int n_in,
                              void* d_out, int out_size, void* d_ws, size_t ws_size,
                              hipStream_t stream) {
    const float* cur = (const float*)d_in[0];
    const float* fs0 = (const float*)d_in[1];
    const float* a   = (const float*)d_in[2];
    const float* b   = (const float*)d_in[3];
    const float* w   = (const float*)d_in[4];
    const float* ds  = (const float*)d_in[5];
    const float* pc  = (const float*)d_in[6];
    const float* gb  = (const float*)d_in[7];
    float* out = (float*)d_out;

    const int threads = 256;
    const int grid = (BB * 16) / threads;  // 512 blocks = 2048 waves, 2/SIMD
    frm_kernel<<<grid, threads, 0, stream>>>(cur, fs0, a, b, w, ds, pc, gb, out);
}

// Round 4
// 226.497 us; speedup vs baseline: 1.3764x; 1.2511x over previous
//
#include <hip/hip_runtime.h>

// FiringRateModel, z-recurrence, 8 lanes/chain, 8 states/lane.
//   sigma_t = d*sigma_{t-1} + c_t*(d*aw) + f_{t-1}*(d*bw)
//   z_{t+1} = Sum(sigma_t) + c_{t+1}*SA + f_t*SB
//   f_t = 200*tanh(max(poly(z_t/100 - g_b/100), 0))
// Two chains share each 16-lane DPP row, interleaved at QUAD granularity
// (chain = quad parity) so the 8-lane allreduce is exactly 3 fused DPP adds:
//   quad_perm[1,0,3,2] + quad_perm[2,3,0,1] + row_ror:8
// 1024 waves total = 1 wave/SIMD; issue-bound on the f32 pipe.

#define TT 2048
#define BB 8192

typedef float v2f __attribute__((ext_vector_type(2)));

__device__ __forceinline__ float dpp_add_x1(float z) {
    float o;
    asm("v_add_f32 %0, %1, %2 quad_perm:[1,0,3,2] row_mask:0xf bank_mask:0xf"
        : "=v"(o) : "v"(z), "v"(z));
    return o;
}
__device__ __forceinline__ float dpp_add_x2(float z) {
    float o;
    asm("v_add_f32 %0, %1, %2 quad_perm:[2,3,0,1] row_mask:0xf bank_mask:0xf"
        : "=v"(o) : "v"(z), "v"(z));
    return o;
}
__device__ __forceinline__ float dpp_add_r8(float z) {
    float o;
    asm("v_add_f32 %0, %1, %2 row_ror:8 row_mask:0xf bank_mask:0xf"
        : "=v"(o) : "v"(z), "v"(z));
    return o;
}
// all-reduce over the 8 lanes of one chain (quad-interleaved layout)
__device__ __forceinline__ float allreduce8(float z) {
    z = dpp_add_x1(z);   // + lane^1         -> pair sums
    z = dpp_add_x2(z);   // + lane^2         -> quad sums
    z = dpp_add_r8(z);   // + quad two apart -> chain total in all 8 lanes
    return z;
}

#define STEP(ccur, cnext, so, FIN, FOUT) do {                           \
    float xx = fmaf(z, 0.01f, ngb01);                                   \
    float x2 = xx * xx;                                                 \
    float t1 = fmaf(k5, xx, k4);                                        \
    float t2 = fmaf(k3, xx, k2);                                        \
    float t3 = fmaf(k1, xx, k0);                                        \
    float pl = fmaf(t1, x2, t2);                                        \
    pl = fmaf(pl, x2, t3);                                              \
    pl = fmaxf(pl, 0.0f);                                               \
    float ee = __builtin_amdgcn_exp2f(pl * -2.885390081777927f);        \
    FOUT = fmaf(ee, -200.0f, 200.0f) * __builtin_amdgcn_rcpf(1.0f + ee);\
    v2f f2 = { FIN, FIN };                                              \
    v2f c2 = { (ccur), (ccur) };                                        \
    sg0 = __builtin_elementwise_fma(d0, sg0,                            \
            __builtin_elementwise_fma(c2, A0, f2 * B0));                \
    sg1 = __builtin_elementwise_fma(d1, sg1,                            \
            __builtin_elementwise_fma(c2, A1, f2 * B1));                \
    sg2 = __builtin_elementwise_fma(d2, sg2,                            \
            __builtin_elementwise_fma(c2, A2, f2 * B2));                \
    sg3 = __builtin_elementwise_fma(d3, sg3,                            \
            __builtin_elementwise_fma(c2, A3, f2 * B3));                \
    v2f ss = (sg0 + sg1) + (sg2 + sg3);                                 \
    float S = allreduce8(ss.x + ss.y);                                  \
    z = fmaf(FOUT, SB, fmaf((cnext), SA, S));                           \
    if (h == 0) outp[obase + (so) * BB + chain] = FOUT;                 \
} while (0)

__global__ __launch_bounds__(256, 1) void frm_kernel(
    const float* __restrict__ cur, const float* __restrict__ fs0,
    const float* __restrict__ av,  const float* __restrict__ bv,
    const float* __restrict__ wv,  const float* __restrict__ dsv,
    const float* __restrict__ pcv, const float* __restrict__ gbv,
    float* __restrict__ outp)
{
    const int tid  = blockIdx.x * 256 + threadIdx.x;
    const int lane = threadIdx.x & 15;        // lane within DPP row
    const int row  = tid >> 4;                // 16-lane row id (0..4095)
    const int sub  = (lane >> 2) & 1;         // chain = quad parity
    const int chain = row * 2 + sub;          // batch index b (0..8191)
    const int h    = ((lane >> 3) << 2) | (lane & 3);  // state-group 0..7

    const int n0 = h * 8;                     // this lane's 8 state indices
    float wk0 = wv[n0+0], wk1 = wv[n0+1], wk2 = wv[n0+2], wk3 = wv[n0+3];
    float wk4 = wv[n0+4], wk5 = wv[n0+5], wk6 = wv[n0+6], wk7 = wv[n0+7];
    float dk0 = 1.0f-dsv[n0+0], dk1 = 1.0f-dsv[n0+1], dk2 = 1.0f-dsv[n0+2], dk3 = 1.0f-dsv[n0+3];
    float dk4 = 1.0f-dsv[n0+4], dk5 = 1.0f-dsv[n0+5], dk6 = 1.0f-dsv[n0+6], dk7 = 1.0f-dsv[n0+7];
    float ak0 = av[n0+0]*wk0, ak1 = av[n0+1]*wk1, ak2 = av[n0+2]*wk2, ak3 = av[n0+3]*wk3;
    float ak4 = av[n0+4]*wk4, ak5 = av[n0+5]*wk5, ak6 = av[n0+6]*wk6, ak7 = av[n0+7]*wk7;
    float bk0 = 1000.0f*bv[n0+0]*wk0, bk1 = 1000.0f*bv[n0+1]*wk1;
    float bk2 = 1000.0f*bv[n0+2]*wk2, bk3 = 1000.0f*bv[n0+3]*wk3;
    float bk4 = 1000.0f*bv[n0+4]*wk4, bk5 = 1000.0f*bv[n0+5]*wk5;
    float bk6 = 1000.0f*bv[n0+6]*wk6, bk7 = 1000.0f*bv[n0+7]*wk7;

    const v2f d0 = {dk0, dk1}, d1 = {dk2, dk3}, d2 = {dk4, dk5}, d3 = {dk6, dk7};
    const v2f A0 = {dk0*ak0, dk1*ak1}, A1 = {dk2*ak2, dk3*ak3};
    const v2f A2 = {dk4*ak4, dk5*ak5}, A3 = {dk6*ak6, dk7*ak7};
    const v2f B0 = {dk0*bk0, dk1*bk1}, B1 = {dk2*bk2, dk3*bk3};
    const v2f B2 = {dk4*bk4, dk5*bk5}, B3 = {dk6*bk6, dk7*bk7};

    const float SA = allreduce8(((ak0+ak1)+(ak2+ak3)) + ((ak4+ak5)+(ak6+ak7)));
    const float SB = allreduce8(((bk0+bk1)+(bk2+bk3)) + ((bk4+bk5)+(bk6+bk7)));

    const float k0 = pcv[0]*pcv[0], k1 = pcv[1]*pcv[1], k2 = pcv[2]*pcv[2];
    const float k3 = pcv[3]*pcv[3], k4 = pcv[4]*pcv[4], k5 = pcv[5]*pcv[5];
    const float ngb01 = -gbv[0] * 0.01f;

    float fA = fs0[chain];
    float fB;
    v2f sg0 = {0,0}, sg1 = {0,0}, sg2 = {0,0}, sg3 = {0,0};

    const float* cpt = cur + chain;

    // prefetch first 16 currents (distance-16 pipeline, two 8-wide banks)
    float P0 = cpt[0*BB], P1 = cpt[1*BB], P2 = cpt[2*BB], P3 = cpt[3*BB];
    float P4 = cpt[4*BB], P5 = cpt[5*BB], P6 = cpt[6*BB], P7 = cpt[7*BB];
    float Q0 = cpt[8*BB], Q1 = cpt[9*BB], Q2 = cpt[10*BB], Q3 = cpt[11*BB];
    float Q4 = cpt[12*BB], Q5 = cpt[13*BB], Q6 = cpt[14*BB], Q7 = cpt[15*BB];

    // z_0 = c_0*SA + fs0*SB  (sigma_{-1} = 0)
    float z = fmaf(fA, SB, P0 * SA);

    int obase = 0;
    for (int t = 0; t + 32 <= TT; t += 16) {
        STEP(P0, P1, 0, fA, fB);  STEP(P1, P2, 1, fB, fA);
        STEP(P2, P3, 2, fA, fB);  STEP(P3, P4, 3, fB, fA);
        STEP(P4, P5, 4, fA, fB);  STEP(P5, P6, 5, fB, fA);
        STEP(P6, P7, 6, fA, fB);  STEP(P7, Q0, 7, fB, fA);
        P0 = cpt[obase + 16*BB]; P1 = cpt[obase + 17*BB];
        P2 = cpt[obase + 18*BB]; P3 = cpt[obase + 19*BB];
        P4 = cpt[obase + 20*BB]; P5 = cpt[obase + 21*BB];
        P6 = cpt[obase + 22*BB]; P7 = cpt[obase + 23*BB];
        STEP(Q0, Q1, 8, fA, fB);  STEP(Q1, Q2, 9, fB, fA);
        STEP(Q2, Q3, 10, fA, fB); STEP(Q3, Q4, 11, fB, fA);
        STEP(Q4, Q5, 12, fA, fB); STEP(Q5, Q6, 13, fB, fA);
        STEP(Q6, Q7, 14, fA, fB); STEP(Q7, P0, 15, fB, fA);
        Q0 = cpt[obase + 24*BB]; Q1 = cpt[obase + 25*BB];
        Q2 = cpt[obase + 26*BB]; Q3 = cpt[obase + 27*BB];
        Q4 = cpt[obase + 28*BB]; Q5 = cpt[obase + 29*BB];
        Q6 = cpt[obase + 30*BB]; Q7 = cpt[obase + 31*BB];
        obase += 16 * BB;
    }
    // epilogue: last 16 steps entirely from registers
    STEP(P0, P1, 0, fA, fB);  STEP(P1, P2, 1, fB, fA);
    STEP(P2, P3, 2, fA, fB);  STEP(P3, P4, 3, fB, fA);
    STEP(P4, P5, 4, fA, fB);  STEP(P5, P6, 5, fB, fA);
    STEP(P6, P7, 6, fA, fB);  STEP(P7, Q0, 7, fB, fA);
    STEP(Q0, Q1, 8, fA, fB);  STEP(Q1, Q2, 9, fB, fA);
    STEP(Q2, Q3, 10, fA, fB); STEP(Q3, Q4, 11, fB, fA);
    STEP(Q4, Q5, 12, fA, fB); STEP(Q5, Q6, 13, fB, fA);
    STEP(Q6, Q7, 14, fA, fB); STEP(Q7, 0.0f, 15, fB, fA);
}

extern "C" void kernel_launch(void* const* d_in, const int* in_sizes, int n_in,
                              void* d_out, int out_size, void* d_ws, size_t ws_size,
                              hipStream_t stream) {
    const float* cur = (const float*)d_in[0];
    const float* fs0 = (const float*)d_in[1];
    const float* a   = (const float*)d_in[2];
    const float* b   = (const float*)d_in[3];
    const float* w   = (const float*)d_in[4];
    const float* ds  = (const float*)d_in[5];
    const float* pc  = (const float*)d_in[6];
    const float* gb  = (const float*)d_in[7];
    float* out = (float*)d_out;

    const int threads = 256;
    const int grid = (BB * 8) / threads;   // 256 blocks = 1024 waves = 1/SIMD
    frm_kernel<<<grid, threads, 0, stream>>>(cur, fs0, a, b, w, ds, pc, gb, out);
}